// Round 6
// baseline (181.284 us; speedup 1.0000x reference)
//
#include <hip/hip_runtime.h>
#include <cstdint>

#define NN 8192
#define NE 65536
#define G 16    // nodes per block in nodeprep
#define CAP 64  // bucket capacity per CSR row (Poisson λ=8 -> P(deg>64) ~ 0)

typedef _Float16 h4 __attribute__((ext_vector_type(4)));
typedef _Float16 h2 __attribute__((ext_vector_type(2)));

// ---------- Threefry-2x32, 20 rounds, JAX-compatible ----------
__host__ __device__ inline void tf2x32(uint32_t k0, uint32_t k1,
                                       uint32_t x0, uint32_t x1,
                                       uint32_t& r0, uint32_t& r1) {
  uint32_t ks2 = k0 ^ k1 ^ 0x1BD11BDAu;
  x0 += k0; x1 += k1;
#define TF_ROT(x,d) (((x)<<(d))|((x)>>(32-(d))))
#define TF_R4(ra,rb,rc,rd) \
  x0+=x1; x1=TF_ROT(x1,ra); x1^=x0; \
  x0+=x1; x1=TF_ROT(x1,rb); x1^=x0; \
  x0+=x1; x1=TF_ROT(x1,rc); x1^=x0; \
  x0+=x1; x1=TF_ROT(x1,rd); x1^=x0;
  TF_R4(13,15,26,6)  x0+=k1;  x1+=ks2+1u;
  TF_R4(17,29,16,24) x0+=ks2; x1+=k0+2u;
  TF_R4(13,15,26,6)  x0+=k0;  x1+=k1+3u;
  TF_R4(17,29,16,24) x0+=k1;  x1+=ks2+4u;
  TF_R4(13,15,26,6)  x0+=ks2; x1+=k0+5u;
  r0=x0; r1=x1;
#undef TF_R4
#undef TF_ROT
}

__device__ inline float gumbel32(uint32_t k0, uint32_t k1, uint32_t idx) {
  uint32_t a, b;
  tf2x32(k0, k1, 0u, idx, a, b);
  uint32_t bits = a ^ b;
  float f = __uint_as_float((bits >> 9) | 0x3f800000u) - 1.0f;
  float u = (f > 0.0f) ? f : 1.17549435e-38f;
  return -logf(-logf(u));
}

// ---------- CSR build (bucketed: count + place in one pass) ----------
__global__ void k_zero(int* __restrict__ p, int n) {
  int i = blockIdx.x*blockDim.x + threadIdx.x;
  if (i < n) p[i] = 0;
}

__global__ void k_scatter(const int* __restrict__ ei, int* __restrict__ cnt,
                          int* __restrict__ csr_col) {
  int e = blockIdx.x*blockDim.x + threadIdx.x;
  if (e < NE) {
    int v = ei[e];
    int pos = atomicAdd(&cnt[v], 1);
    if (pos < CAP) csr_col[(v<<6) + pos] = ei[NE + e];
  }
}

// ---------- per-node precompute + layer-0 gumbel gates (16 nodes/block) ----------
// outputs: xs, rres, delta (fp32); dxh2 (fp16 pairs {d,d+64}); Bm (fp32), Bh (fp16), Cm;
// gates inp/outp; block 0 preps Amat = -exp(A_log)
__global__ __launch_bounds__(256) void k_nodeprep(
    const float* __restrict__ x, const float* __restrict__ ipw,
    const float* __restrict__ xpw, const float* __restrict__ dtw,
    const float* __restrict__ iaw, const float* __restrict__ iab,
    const float* __restrict__ oaw, const float* __restrict__ oab,
    const float* __restrict__ alog,
    uint32_t ki0, uint32_t ki1, uint32_t ko0, uint32_t ko1,
    float* __restrict__ xs, float* __restrict__ rres,
    float* __restrict__ delta, _Float16* __restrict__ dxh2,
    float* __restrict__ Bm, _Float16* __restrict__ Bh,
    float* __restrict__ Cm,
    float* __restrict__ inp, float* __restrict__ outp,
    float* __restrict__ Amat) {
  __shared__ float sx[G][64];
  __shared__ float sxs[G][128];
  __shared__ float sdbl[G][36];
  __shared__ float sdx[2][128];
  __shared__ float4 sred4[4];
  int t = threadIdx.x;
  int b0 = blockIdx.x * G;
  if (blockIdx.x == 0) {
    for (int i = t; i < 2048; i += 256) Amat[i] = -expf(alog[i]);
  }
  for (int i = t; i < G*64; i += 256) sx[i>>6][i&63] = x[b0*64 + i];
  __syncthreads();
  // GEMM1: [G x 64] @ [64 x 256]; thread owns column t for all G nodes
  float acc[G];
#pragma unroll
  for (int g = 0; g < G; g++) acc[g] = 0.f;
  for (int k = 0; k < 64; k++) {
    float w = ipw[k*256 + t];
#pragma unroll
    for (int g = 0; g < G; g++) acc[g] += sx[g][k] * w;
  }
  if (t < 128) {
#pragma unroll
    for (int g = 0; g < G; g++) {
      float v = fmaxf(acc[g], 0.f);
      sxs[g][t] = v;
      xs[(size_t)(b0+g)*128 + t] = v;
    }
  } else {
    int j = t - 128;
#pragma unroll
    for (int g = 0; g < G; g++) rres[(size_t)(b0+g)*128 + j] = fmaxf(acc[g], 0.f);
  }
  __syncthreads();
  // GEMM2: x_dbl [G x 36]
  for (int idx = t; idx < G*36; idx += 256) {
    int g = idx / 36, c = idx % 36;
    float a = 0.f;
    for (int d = 0; d < 128; d++) a += sxs[g][d] * xpw[d*36 + c];
    sdbl[g][c] = a;
    if (c >= 4 && c < 20) {
      Bm[(b0+g)*16 + (c-4)] = a;
      Bh[(b0+g)*16 + (c-4)] = (_Float16)a;
    } else if (c >= 20)    Cm[(b0+g)*16 + (c-20)] = a;
  }
  __syncthreads();
  // GEMM3 + softplus + dxh2 pack + gates; halves (threads 0-127 / 128-255) each do G/2 nodes
  int d = t & 127;
  int hi = t >> 7;
  int lane = t & 63, wv = t >> 6;
  for (int gg = 0; gg < G/2; gg++) {
    int g = hi*(G/2) + gg;
    int b = b0 + g;
    float dt = sdbl[g][0]*dtw[d]     + sdbl[g][1]*dtw[128+d]
             + sdbl[g][2]*dtw[256+d] + sdbl[g][3]*dtw[384+d];
    float dv = fmaxf(dt, 0.f) + log1pf(expf(-fabsf(dt)));  // softplus
    delta[(size_t)b*128 + d] = dv;
    float dxv = dv * sxs[g][d];
    sdx[hi][d] = dxv;
    float4 pr;
    pr.x = dxv * iaw[2*d];   pr.y = dxv * iaw[2*d+1];
    pr.z = dxv * oaw[2*d];   pr.w = dxv * oaw[2*d+1];
    for (int off = 32; off >= 1; off >>= 1) {
      pr.x += __shfl_down(pr.x, off);
      pr.y += __shfl_down(pr.y, off);
      pr.z += __shfl_down(pr.z, off);
      pr.w += __shfl_down(pr.w, off);
    }
    if (lane == 0) sred4[wv] = pr;
    __syncthreads();
    if (d < 64) {
      h2 pk;
      pk.x = (_Float16)sdx[hi][d];
      pk.y = (_Float16)sdx[hi][d + 64];
      ((h2*)(dxh2 + ((size_t)b << 7)))[d] = pk;
    }
    if (d == 0) {
      float4 q0 = sred4[hi*2], q1 = sred4[hi*2 + 1];
      float BC = 0.f;
      for (int n = 0; n < 16; n++) BC += sdbl[g][4+n] * sdbl[g][20+n];
      float li0 = BC*(q0.x+q1.x) + iab[0], li1 = BC*(q0.y+q1.y) + iab[1];
      float lo0 = BC*(q0.z+q1.z) + oab[0], lo1 = BC*(q0.w+q1.w) + oab[1];
      uint32_t L0 = 2u*(uint32_t)b, L1 = L0 + 1u;
      inp[b]  = (li0 + gumbel32(ki0, ki1, L0) >= li1 + gumbel32(ki0, ki1, L1)) ? 1.0f : 0.0f;
      outp[b] = (lo0 + gumbel32(ko0, ko1, L0) >= lo1 + gumbel32(ko0, ko1, L1)) ? 1.0f : 0.0f;
    }
    __syncthreads();
  }
}

// ---------- fused spmm0 (rank-1 gather, fp16 operands) + layer-1 update + deg1 + layer-2 self-term ----------
__global__ __launch_bounds__(256) void k_spmm0f(
    const int* __restrict__ cnt, const int* __restrict__ csr_col,
    const float* __restrict__ inp, const float* __restrict__ outp,
    const float* __restrict__ delta, const _Float16* __restrict__ dxh2,
    const float* __restrict__ Bm, const _Float16* __restrict__ Bh,
    const float* __restrict__ Cm, const float* __restrict__ Amat,
    _Float16* __restrict__ s_out, float* __restrict__ dinv1,
    float* __restrict__ y2p) {
  __shared__ int   sc[CAP];
  __shared__ float scoef[CAP];
  __shared__ float sgate[CAP];
  __shared__ float sdegs;
  int v = blockIdx.x, t = threadIdx.x;
  int deg = min(cnt[v], CAP);
  if (t < deg) {
    int c = csr_col[(v<<6) + t];
    sc[t] = c;
    scoef[t] = 1.0f / sqrtf((float)min(cnt[c], CAP) + 1.0f);
    sgate[t] = inp[c];
  }
  __syncthreads();
  if (t < 64) {
    float g = (t < deg) ? sgate[t] : 0.f;
    for (int off = 32; off >= 1; off >>= 1) g += __shfl_down(g, off);
    if (t == 0) sdegs = g;
  }
  int d0 = t >> 2, d1 = d0 + 64, nb = t & 3;
  float dv = 1.0f / sqrtf((float)deg + 1.0f);
  float4 Bv = ((const float4*)(Bm + ((size_t)v << 4)))[nb];
  h2 pkv = ((const h2*)(dxh2 + ((size_t)v << 7)))[d0];
  float dx0 = (float)pkv.x, dx1 = (float)pkv.y;
  float dw = dv * dv;
  float c0 = dw * dx0, c1 = dw * dx1;
  float4 a0 = {c0*Bv.x, c0*Bv.y, c0*Bv.z, c0*Bv.w};
  float4 a1 = {c1*Bv.x, c1*Bv.y, c1*Bv.z, c1*Bv.w};
  for (int j = 0; j < deg; j++) {
    int c = sc[j];
    float coef = dv * scoef[j];
    h2 pk = ((const h2*)(dxh2 + ((size_t)c << 7)))[d0];
    h4 Bp = ((const h4*)(Bh + ((size_t)c << 4)))[nb];
    float e0 = coef * (float)pk.x;
    float e1 = coef * (float)pk.y;
    float bx = (float)Bp.x, by = (float)Bp.y, bz = (float)Bp.z, bw = (float)Bp.w;
    a0.x += e0*bx; a0.y += e0*by; a0.z += e0*bz; a0.w += e0*bw;
    a1.x += e1*bx; a1.y += e1*by; a1.z += e1*bz; a1.w += e1*bw;
  }
  float de0 = delta[v*128 + d0], de1 = delta[v*128 + d1];
  float4 A0 = ((const float4*)(Amat + (d0 << 4)))[nb];
  float4 A1 = ((const float4*)(Amat + (d1 << 4)))[nb];
  float4 E0, E1;
  E0.x = expf(de0*A0.x); E0.y = expf(de0*A0.y); E0.z = expf(de0*A0.z); E0.w = expf(de0*A0.w);
  E1.x = expf(de1*A1.x); E1.y = expf(de1*A1.y); E1.z = expf(de1*A1.z); E1.w = expf(de1*A1.w);
  float4 s0, s1;
  s0.x = E0.x*a0.x + dx0*Bv.x;  s0.y = E0.y*a0.y + dx0*Bv.y;
  s0.z = E0.z*a0.z + dx0*Bv.z;  s0.w = E0.w*a0.w + dx0*Bv.w;
  s1.x = E1.x*a1.x + dx1*Bv.x;  s1.y = E1.y*a1.y + dx1*Bv.y;
  s1.z = E1.z*a1.z + dx1*Bv.z;  s1.w = E1.w*a1.w + dx1*Bv.w;
  if (inp[v] != 0.f) {
    h4* op = (h4*)(s_out + ((size_t)v << 11));
    h4 h0, h1;
    h0.x = (_Float16)s0.x; h0.y = (_Float16)s0.y; h0.z = (_Float16)s0.z; h0.w = (_Float16)s0.w;
    h1.x = (_Float16)s1.x; h1.y = (_Float16)s1.y; h1.z = (_Float16)s1.z; h1.w = (_Float16)s1.w;
    op[t] = h0; op[t + 256] = h1;
  }
  __syncthreads();
  float degs = sdegs;
  float d1v = 1.0f / sqrtf(outp[v]*degs + 1.0f);
  if (t == 0) dinv1[v] = d1v;
  float dw1 = d1v * d1v;
  float4 Cv = ((const float4*)(Cm + ((size_t)v << 4)))[nb];
  float y0p = dw1*(E0.x*s0.x*Cv.x + E0.y*s0.y*Cv.y + E0.z*s0.z*Cv.z + E0.w*s0.w*Cv.w)
            + dx0*(Bv.x*Cv.x + Bv.y*Cv.y + Bv.z*Cv.z + Bv.w*Cv.w);
  float y1p = dw1*(E1.x*s1.x*Cv.x + E1.y*s1.y*Cv.y + E1.z*s1.z*Cv.z + E1.w*s1.w*Cv.w)
            + dx1*(Bv.x*Cv.x + Bv.y*Cv.y + Bv.z*Cv.z + Bv.w*Cv.w);
  y0p += __shfl_xor(y0p, 1); y0p += __shfl_xor(y0p, 2);
  y1p += __shfl_xor(y1p, 1); y1p += __shfl_xor(y1p, 2);
  if (nb == 0) {
    y2p[v*128 + d0] = y0p;
    y2p[v*128 + d1] = y1p;
  }
}

// ---------- fused gated spmm1 + layer-2 + output projection ----------
__global__ __launch_bounds__(256) void k_spmm1fo(
    const int* __restrict__ cnt, const int* __restrict__ csr_col,
    const float* __restrict__ dinv1,
    const float* __restrict__ inp, const float* __restrict__ outp,
    const float* __restrict__ delta,
    const float* __restrict__ Cm, const float* __restrict__ Amat,
    const _Float16* __restrict__ s_in, const float* __restrict__ y2p,
    const float* __restrict__ xs, const float* __restrict__ rres,
    const float* __restrict__ Dv, const float* __restrict__ wout,
    float* __restrict__ out) {
  __shared__ int   sc[CAP];
  __shared__ float scoef[CAP];
  __shared__ int   snact;
  __shared__ float ty[128];
  int v = blockIdx.x, t = threadIdx.x;
  if (t == 0) snact = 0;
  __syncthreads();
  int deg = (outp[v] != 0.f) ? min(cnt[v], CAP) : 0;
  if (t < deg) {
    int c = csr_col[(v<<6) + t];
    if (inp[c] != 0.f) {
      int p = atomicAdd(&snact, 1);
      sc[p] = c; scoef[p] = dinv1[c];
    }
  }
  __syncthreads();
  int nact = snact;
  int d0 = t >> 2, d1 = d0 + 64, nb = t & 3;
  float dv = dinv1[v];
  float4 a0 = {0.f,0.f,0.f,0.f}, a1 = {0.f,0.f,0.f,0.f};
  for (int j = 0; j < nact; j++) {
    int c = sc[j];
    float coef = dv * scoef[j];
    const h4* nbp = (const h4*)(s_in + ((size_t)c << 11));
    h4 n0 = nbp[t], n1 = nbp[t + 256];
    a0.x += coef*(float)n0.x; a0.y += coef*(float)n0.y;
    a0.z += coef*(float)n0.z; a0.w += coef*(float)n0.w;
    a1.x += coef*(float)n1.x; a1.y += coef*(float)n1.y;
    a1.z += coef*(float)n1.z; a1.w += coef*(float)n1.w;
  }
  float y0g = 0.f, y1g = 0.f;
  if (nact > 0) {
    float de0 = delta[v*128 + d0], de1 = delta[v*128 + d1];
    float4 A0 = ((const float4*)(Amat + (d0 << 4)))[nb];
    float4 A1 = ((const float4*)(Amat + (d1 << 4)))[nb];
    float4 Cv = ((const float4*)(Cm + ((size_t)v << 4)))[nb];
    y0g = expf(de0*A0.x)*a0.x*Cv.x + expf(de0*A0.y)*a0.y*Cv.y +
          expf(de0*A0.z)*a0.z*Cv.z + expf(de0*A0.w)*a0.w*Cv.w;
    y1g = expf(de1*A1.x)*a1.x*Cv.x + expf(de1*A1.y)*a1.y*Cv.y +
          expf(de1*A1.z)*a1.z*Cv.z + expf(de1*A1.w)*a1.w*Cv.w;
  }
  y0g += __shfl_xor(y0g, 1); y0g += __shfl_xor(y0g, 2);
  y1g += __shfl_xor(y1g, 1); y1g += __shfl_xor(y1g, 2);
  if (nb == 0) {
    float yA = y0g + y2p[v*128 + d0];
    float yB = y1g + y2p[v*128 + d1];
    ty[d0] = (yA + xs[v*128 + d0]*Dv[d0]) * rres[v*128 + d0];
    ty[d1] = (yB + xs[v*128 + d1]*Dv[d1]) * rres[v*128 + d1];
  }
  __syncthreads();
  if (t < 64) {
    float acc = 0.f;
    for (int d = 0; d < 128; d++) acc += ty[d] * wout[d*64 + t];
    out[v*64 + t] = acc;
  }
}

extern "C" void kernel_launch(void* const* d_in, const int* in_sizes, int n_in,
                              void* d_out, int out_size, void* d_ws, size_t ws_size,
                              hipStream_t stream) {
  const float* x    = (const float*)d_in[0];
  const float* ipw  = (const float*)d_in[1];
  const float* xpw  = (const float*)d_in[2];
  const float* dtw  = (const float*)d_in[3];
  const float* alog = (const float*)d_in[4];
  const float* Dv   = (const float*)d_in[5];
  const float* wout = (const float*)d_in[6];
  const float* iaw  = (const float*)d_in[7];
  const float* iab  = (const float*)d_in[8];
  const float* oaw  = (const float*)d_in[9];
  const float* oab  = (const float*)d_in[10];
  const int*   ei   = (const int*)d_in[11];
  (void)in_sizes; (void)n_in; (void)out_size; (void)ws_size;

  float* W = (float*)d_ws;
  size_t o = 0;
  float* xs    = W + o; o += (size_t)NN*128;
  float* rres  = W + o; o += (size_t)NN*128;
  float* delta = W + o; o += (size_t)NN*128;
  float* y2p   = W + o; o += (size_t)NN*128;
  float* Bm    = W + o; o += (size_t)NN*16;
  float* Cm    = W + o; o += (size_t)NN*16;
  float* Amat  = W + o; o += 2048;
  float* dinv1 = W + o; o += NN;
  float* inp   = W + o; o += NN;
  float* outp  = W + o; o += NN;
  _Float16* dxh2 = (_Float16*)(W + o); o += (size_t)NN*64;   // 2 MB (128 h/row)
  _Float16* Bh   = (_Float16*)(W + o); o += (size_t)NN*8;    // 256 KB
  _Float16* stA  = (_Float16*)(W + o); o += (size_t)NN*1024; // fp16 state1, 32 MB
  int* cnt     = (int*)(W + o);
  int* csr_col = cnt + NN;

  uint32_t ki0, ki1, ko0, ko1;
  tf2x32(0u, 42u, 0u, 0u, ki0, ki1);
  tf2x32(0u, 42u, 0u, 1u, ko0, ko1);

  // CSR build: zero counters, then bucket-scatter
  k_zero<<<NN/256, 256, 0, stream>>>(cnt, NN);
  k_scatter<<<NE/256, 256, 0, stream>>>(ei, cnt, csr_col);

  // per-node precompute + layer-0 gates + Amat (16 nodes/block)
  k_nodeprep<<<NN/G, 256, 0, stream>>>(x, ipw, xpw, dtw, iaw, iab, oaw, oab,
                                       alog, ki0, ki1, ko0, ko1,
                                       xs, rres, delta, dxh2, Bm, Bh, Cm,
                                       inp, outp, Amat);

  // spmm0 (rank-1, fp16 gather) + layer-1 update + deg1 + layer-2 self-term
  k_spmm0f<<<NN, 256, 0, stream>>>(cnt, csr_col, inp, outp,
                                   delta, dxh2, Bm, Bh, Cm, Amat,
                                   stA, dinv1, y2p);

  // gated gather + layer-2 + output projection
  k_spmm1fo<<<NN, 256, 0, stream>>>(cnt, csr_col, dinv1, inp, outp,
                                    delta, Cm, Amat, stA, y2p,
                                    xs, rres, Dv, wout, (float*)d_out);
}

// Round 7
// 168.666 us; speedup vs baseline: 1.0748x; 1.0748x over previous
//
#include <hip/hip_runtime.h>
#include <cstdint>

#define NN 8192
#define NE 65536
#define G 8     // nodes per block in nodeprep (1024 blocks = 4/CU; G=16 regressed: latency-bound)
#define CAP 64  // bucket capacity per CSR row (Poisson λ=8 -> P(deg>64) ~ 0)

typedef _Float16 h4 __attribute__((ext_vector_type(4)));
typedef _Float16 h2 __attribute__((ext_vector_type(2)));

// ---------- Threefry-2x32, 20 rounds, JAX-compatible ----------
__host__ __device__ inline void tf2x32(uint32_t k0, uint32_t k1,
                                       uint32_t x0, uint32_t x1,
                                       uint32_t& r0, uint32_t& r1) {
  uint32_t ks2 = k0 ^ k1 ^ 0x1BD11BDAu;
  x0 += k0; x1 += k1;
#define TF_ROT(x,d) (((x)<<(d))|((x)>>(32-(d))))
#define TF_R4(ra,rb,rc,rd) \
  x0+=x1; x1=TF_ROT(x1,ra); x1^=x0; \
  x0+=x1; x1=TF_ROT(x1,rb); x1^=x0; \
  x0+=x1; x1=TF_ROT(x1,rc); x1^=x0; \
  x0+=x1; x1=TF_ROT(x1,rd); x1^=x0;
  TF_R4(13,15,26,6)  x0+=k1;  x1+=ks2+1u;
  TF_R4(17,29,16,24) x0+=ks2; x1+=k0+2u;
  TF_R4(13,15,26,6)  x0+=k0;  x1+=k1+3u;
  TF_R4(17,29,16,24) x0+=k1;  x1+=ks2+4u;
  TF_R4(13,15,26,6)  x0+=ks2; x1+=k0+5u;
  r0=x0; r1=x1;
#undef TF_R4
#undef TF_ROT
}

__device__ inline float gumbel32(uint32_t k0, uint32_t k1, uint32_t idx) {
  uint32_t a, b;
  tf2x32(k0, k1, 0u, idx, a, b);
  uint32_t bits = a ^ b;
  float f = __uint_as_float((bits >> 9) | 0x3f800000u) - 1.0f;
  float u = (f > 0.0f) ? f : 1.17549435e-38f;
  return -logf(-logf(u));
}

// ---------- CSR build (bucketed: count + place in one pass) ----------
__global__ void k_zero(int* __restrict__ p, int n) {
  int i = blockIdx.x*blockDim.x + threadIdx.x;
  if (i < n) p[i] = 0;
}

__global__ void k_scatter(const int* __restrict__ ei, int* __restrict__ cnt,
                          int* __restrict__ csr_col) {
  int e = blockIdx.x*blockDim.x + threadIdx.x;
  if (e < NE) {
    int v = ei[e];
    int pos = atomicAdd(&cnt[v], 1);
    if (pos < CAP) csr_col[(v<<6) + pos] = ei[NE + e];
  }
}

// ---------- per-node precompute + layer-0 gumbel gates (8 nodes/block) ----------
// outputs: xs, rres, delta (fp32); dxh2 (fp16 pairs {d,d+64}); Bm (fp32), Bh (fp16), Cm;
// gates inp/outp; block 0 preps Amat = -exp(A_log)
__global__ __launch_bounds__(256) void k_nodeprep(
    const float* __restrict__ x, const float* __restrict__ ipw,
    const float* __restrict__ xpw, const float* __restrict__ dtw,
    const float* __restrict__ iaw, const float* __restrict__ iab,
    const float* __restrict__ oaw, const float* __restrict__ oab,
    const float* __restrict__ alog,
    uint32_t ki0, uint32_t ki1, uint32_t ko0, uint32_t ko1,
    float* __restrict__ xs, float* __restrict__ rres,
    float* __restrict__ delta, _Float16* __restrict__ dxh2,
    float* __restrict__ Bm, _Float16* __restrict__ Bh,
    float* __restrict__ Cm,
    float* __restrict__ inp, float* __restrict__ outp,
    float* __restrict__ Amat) {
  __shared__ float sx[G][64];
  __shared__ float sxs[G][128];
  __shared__ float sdbl[G][36];
  __shared__ float sdx[G][128];
  int t = threadIdx.x;
  int b0 = blockIdx.x * G;
  if (blockIdx.x == 0) {
    for (int i = t; i < 2048; i += 256) Amat[i] = -expf(alog[i]);
  }
  for (int i = t; i < G*64; i += 256) sx[i>>6][i&63] = x[b0*64 + i];
  __syncthreads();
  // GEMM1: [G x 64] @ [64 x 256]; thread owns column t for all G nodes
  float acc[G];
#pragma unroll
  for (int g = 0; g < G; g++) acc[g] = 0.f;
  for (int k = 0; k < 64; k++) {
    float w = ipw[k*256 + t];
#pragma unroll
    for (int g = 0; g < G; g++) acc[g] += sx[g][k] * w;
  }
  if (t < 128) {
#pragma unroll
    for (int g = 0; g < G; g++) {
      float v = fmaxf(acc[g], 0.f);
      sxs[g][t] = v;
      xs[(size_t)(b0+g)*128 + t] = v;
    }
  } else {
    int j = t - 128;
#pragma unroll
    for (int g = 0; g < G; g++) rres[(size_t)(b0+g)*128 + j] = fmaxf(acc[g], 0.f);
  }
  __syncthreads();
  // GEMM2: x_dbl [G x 36]
  for (int idx = t; idx < G*36; idx += 256) {
    int g = idx / 36, c = idx % 36;
    float a = 0.f;
    for (int d = 0; d < 128; d++) a += sxs[g][d] * xpw[d*36 + c];
    sdbl[g][c] = a;
    if (c >= 4 && c < 20) {
      Bm[(b0+g)*16 + (c-4)] = a;
      Bh[(b0+g)*16 + (c-4)] = (_Float16)a;
    } else if (c >= 20)    Cm[(b0+g)*16 + (c-20)] = a;
  }
  __syncthreads();
  // GEMM3: softplus(delta) + dxs -> sdx; no reductions, no syncs inside loop
  {
    int d = t & 127, hi = t >> 7;
#pragma unroll
    for (int gg = 0; gg < G/2; gg++) {
      int g = hi*(G/2) + gg;
      int b = b0 + g;
      float dt = sdbl[g][0]*dtw[d]     + sdbl[g][1]*dtw[128+d]
               + sdbl[g][2]*dtw[256+d] + sdbl[g][3]*dtw[384+d];
      float dv = fmaxf(dt, 0.f) + log1pf(expf(-fabsf(dt)));  // softplus
      delta[(size_t)b*128 + d] = dv;
      sdx[g][d] = dv * sxs[g][d];
    }
  }
  __syncthreads();
  // Phase E: dxh2 pack (all threads) + gates (one node per wave per step, wave-local)
  for (int i = t; i < G*64; i += 256) {
    int g = i >> 6, d = i & 63;
    h2 pk;
    pk.x = (_Float16)sdx[g][d];
    pk.y = (_Float16)sdx[g][d + 64];
    ((h2*)(dxh2 + ((size_t)(b0+g) << 7)))[d] = pk;
  }
  int wid = t >> 6, lane = t & 63;
#pragma unroll
  for (int s = 0; s < 2; s++) {
    int g = wid*2 + s;
    int b = b0 + g;
    float da = sdx[g][lane], db = sdx[g][lane + 64];
    float4 pr;
    pr.x = da*iaw[2*lane]   + db*iaw[2*(lane+64)];
    pr.y = da*iaw[2*lane+1] + db*iaw[2*(lane+64)+1];
    pr.z = da*oaw[2*lane]   + db*oaw[2*(lane+64)];
    pr.w = da*oaw[2*lane+1] + db*oaw[2*(lane+64)+1];
    for (int off = 32; off >= 1; off >>= 1) {
      pr.x += __shfl_down(pr.x, off);
      pr.y += __shfl_down(pr.y, off);
      pr.z += __shfl_down(pr.z, off);
      pr.w += __shfl_down(pr.w, off);
    }
    if (lane == 0) {
      float BC = 0.f;
      for (int n = 0; n < 16; n++) BC += sdbl[g][4+n] * sdbl[g][20+n];
      float li0 = BC*pr.x + iab[0], li1 = BC*pr.y + iab[1];
      float lo0 = BC*pr.z + oab[0], lo1 = BC*pr.w + oab[1];
      uint32_t L0 = 2u*(uint32_t)b, L1 = L0 + 1u;
      inp[b]  = (li0 + gumbel32(ki0, ki1, L0) >= li1 + gumbel32(ki0, ki1, L1)) ? 1.0f : 0.0f;
      outp[b] = (lo0 + gumbel32(ko0, ko1, L0) >= lo1 + gumbel32(ko0, ko1, L1)) ? 1.0f : 0.0f;
    }
  }
}

// ---------- fused spmm0 (rank-1 gather, fp16 operands) + layer-1 update + deg1 + layer-2 self-term ----------
__global__ __launch_bounds__(256) void k_spmm0f(
    const int* __restrict__ cnt, const int* __restrict__ csr_col,
    const float* __restrict__ inp, const float* __restrict__ outp,
    const float* __restrict__ delta, const _Float16* __restrict__ dxh2,
    const float* __restrict__ Bm, const _Float16* __restrict__ Bh,
    const float* __restrict__ Cm, const float* __restrict__ Amat,
    _Float16* __restrict__ s_out, float* __restrict__ dinv1,
    float* __restrict__ y2p) {
  __shared__ int   sc[CAP];
  __shared__ float scoef[CAP];
  __shared__ float sgate[CAP];
  __shared__ float sdegs;
  int v = blockIdx.x, t = threadIdx.x;
  int deg = min(cnt[v], CAP);
  if (t < deg) {
    int c = csr_col[(v<<6) + t];
    sc[t] = c;
    scoef[t] = 1.0f / sqrtf((float)min(cnt[c], CAP) + 1.0f);
    sgate[t] = inp[c];
  }
  __syncthreads();
  if (t < 64) {
    float g = (t < deg) ? sgate[t] : 0.f;
    for (int off = 32; off >= 1; off >>= 1) g += __shfl_down(g, off);
    if (t == 0) sdegs = g;
  }
  int d0 = t >> 2, d1 = d0 + 64, nb = t & 3;
  float dv = 1.0f / sqrtf((float)deg + 1.0f);
  float4 Bv = ((const float4*)(Bm + ((size_t)v << 4)))[nb];
  h2 pkv = ((const h2*)(dxh2 + ((size_t)v << 7)))[d0];
  float dx0 = (float)pkv.x, dx1 = (float)pkv.y;
  float dw = dv * dv;
  float c0 = dw * dx0, c1 = dw * dx1;
  float4 a0 = {c0*Bv.x, c0*Bv.y, c0*Bv.z, c0*Bv.w};
  float4 a1 = {c1*Bv.x, c1*Bv.y, c1*Bv.z, c1*Bv.w};
  for (int j = 0; j < deg; j++) {
    int c = sc[j];
    float coef = dv * scoef[j];
    h2 pk = ((const h2*)(dxh2 + ((size_t)c << 7)))[d0];
    h4 Bp = ((const h4*)(Bh + ((size_t)c << 4)))[nb];
    float e0 = coef * (float)pk.x;
    float e1 = coef * (float)pk.y;
    float bx = (float)Bp.x, by = (float)Bp.y, bz = (float)Bp.z, bw = (float)Bp.w;
    a0.x += e0*bx; a0.y += e0*by; a0.z += e0*bz; a0.w += e0*bw;
    a1.x += e1*bx; a1.y += e1*by; a1.z += e1*bz; a1.w += e1*bw;
  }
  float de0 = delta[v*128 + d0], de1 = delta[v*128 + d1];
  float4 A0 = ((const float4*)(Amat + (d0 << 4)))[nb];
  float4 A1 = ((const float4*)(Amat + (d1 << 4)))[nb];
  float4 E0, E1;
  E0.x = expf(de0*A0.x); E0.y = expf(de0*A0.y); E0.z = expf(de0*A0.z); E0.w = expf(de0*A0.w);
  E1.x = expf(de1*A1.x); E1.y = expf(de1*A1.y); E1.z = expf(de1*A1.z); E1.w = expf(de1*A1.w);
  float4 s0, s1;
  s0.x = E0.x*a0.x + dx0*Bv.x;  s0.y = E0.y*a0.y + dx0*Bv.y;
  s0.z = E0.z*a0.z + dx0*Bv.z;  s0.w = E0.w*a0.w + dx0*Bv.w;
  s1.x = E1.x*a1.x + dx1*Bv.x;  s1.y = E1.y*a1.y + dx1*Bv.y;
  s1.z = E1.z*a1.z + dx1*Bv.z;  s1.w = E1.w*a1.w + dx1*Bv.w;
  if (inp[v] != 0.f) {
    h4* op = (h4*)(s_out + ((size_t)v << 11));
    h4 h0, h1;
    h0.x = (_Float16)s0.x; h0.y = (_Float16)s0.y; h0.z = (_Float16)s0.z; h0.w = (_Float16)s0.w;
    h1.x = (_Float16)s1.x; h1.y = (_Float16)s1.y; h1.z = (_Float16)s1.z; h1.w = (_Float16)s1.w;
    op[t] = h0; op[t + 256] = h1;
  }
  __syncthreads();
  float degs = sdegs;
  float d1v = 1.0f / sqrtf(outp[v]*degs + 1.0f);
  if (t == 0) dinv1[v] = d1v;
  float dw1 = d1v * d1v;
  float4 Cv = ((const float4*)(Cm + ((size_t)v << 4)))[nb];
  float y0p = dw1*(E0.x*s0.x*Cv.x + E0.y*s0.y*Cv.y + E0.z*s0.z*Cv.z + E0.w*s0.w*Cv.w)
            + dx0*(Bv.x*Cv.x + Bv.y*Cv.y + Bv.z*Cv.z + Bv.w*Cv.w);
  float y1p = dw1*(E1.x*s1.x*Cv.x + E1.y*s1.y*Cv.y + E1.z*s1.z*Cv.z + E1.w*s1.w*Cv.w)
            + dx1*(Bv.x*Cv.x + Bv.y*Cv.y + Bv.z*Cv.z + Bv.w*Cv.w);
  y0p += __shfl_xor(y0p, 1); y0p += __shfl_xor(y0p, 2);
  y1p += __shfl_xor(y1p, 1); y1p += __shfl_xor(y1p, 2);
  if (nb == 0) {
    y2p[v*128 + d0] = y0p;
    y2p[v*128 + d1] = y1p;
  }
}

// ---------- fused gated spmm1 + layer-2 + output projection ----------
__global__ __launch_bounds__(256) void k_spmm1fo(
    const int* __restrict__ cnt, const int* __restrict__ csr_col,
    const float* __restrict__ dinv1,
    const float* __restrict__ inp, const float* __restrict__ outp,
    const float* __restrict__ delta,
    const float* __restrict__ Cm, const float* __restrict__ Amat,
    const _Float16* __restrict__ s_in, const float* __restrict__ y2p,
    const float* __restrict__ xs, const float* __restrict__ rres,
    const float* __restrict__ Dv, const float* __restrict__ wout,
    float* __restrict__ out) {
  __shared__ int   sc[CAP];
  __shared__ float scoef[CAP];
  __shared__ int   snact;
  __shared__ float ty[128];
  int v = blockIdx.x, t = threadIdx.x;
  if (t == 0) snact = 0;
  __syncthreads();
  int deg = (outp[v] != 0.f) ? min(cnt[v], CAP) : 0;
  if (t < deg) {
    int c = csr_col[(v<<6) + t];
    if (inp[c] != 0.f) {
      int p = atomicAdd(&snact, 1);
      sc[p] = c; scoef[p] = dinv1[c];
    }
  }
  __syncthreads();
  int nact = snact;
  int d0 = t >> 2, d1 = d0 + 64, nb = t & 3;
  float dv = dinv1[v];
  float4 a0 = {0.f,0.f,0.f,0.f}, a1 = {0.f,0.f,0.f,0.f};
  for (int j = 0; j < nact; j++) {
    int c = sc[j];
    float coef = dv * scoef[j];
    const h4* nbp = (const h4*)(s_in + ((size_t)c << 11));
    h4 n0 = nbp[t], n1 = nbp[t + 256];
    a0.x += coef*(float)n0.x; a0.y += coef*(float)n0.y;
    a0.z += coef*(float)n0.z; a0.w += coef*(float)n0.w;
    a1.x += coef*(float)n1.x; a1.y += coef*(float)n1.y;
    a1.z += coef*(float)n1.z; a1.w += coef*(float)n1.w;
  }
  float y0g = 0.f, y1g = 0.f;
  if (nact > 0) {
    float de0 = delta[v*128 + d0], de1 = delta[v*128 + d1];
    float4 A0 = ((const float4*)(Amat + (d0 << 4)))[nb];
    float4 A1 = ((const float4*)(Amat + (d1 << 4)))[nb];
    float4 Cv = ((const float4*)(Cm + ((size_t)v << 4)))[nb];
    y0g = expf(de0*A0.x)*a0.x*Cv.x + expf(de0*A0.y)*a0.y*Cv.y +
          expf(de0*A0.z)*a0.z*Cv.z + expf(de0*A0.w)*a0.w*Cv.w;
    y1g = expf(de1*A1.x)*a1.x*Cv.x + expf(de1*A1.y)*a1.y*Cv.y +
          expf(de1*A1.z)*a1.z*Cv.z + expf(de1*A1.w)*a1.w*Cv.w;
  }
  y0g += __shfl_xor(y0g, 1); y0g += __shfl_xor(y0g, 2);
  y1g += __shfl_xor(y1g, 1); y1g += __shfl_xor(y1g, 2);
  if (nb == 0) {
    float yA = y0g + y2p[v*128 + d0];
    float yB = y1g + y2p[v*128 + d1];
    ty[d0] = (yA + xs[v*128 + d0]*Dv[d0]) * rres[v*128 + d0];
    ty[d1] = (yB + xs[v*128 + d1]*Dv[d1]) * rres[v*128 + d1];
  }
  __syncthreads();
  if (t < 64) {
    float acc = 0.f;
    for (int d = 0; d < 128; d++) acc += ty[d] * wout[d*64 + t];
    out[v*64 + t] = acc;
  }
}

extern "C" void kernel_launch(void* const* d_in, const int* in_sizes, int n_in,
                              void* d_out, int out_size, void* d_ws, size_t ws_size,
                              hipStream_t stream) {
  const float* x    = (const float*)d_in[0];
  const float* ipw  = (const float*)d_in[1];
  const float* xpw  = (const float*)d_in[2];
  const float* dtw  = (const float*)d_in[3];
  const float* alog = (const float*)d_in[4];
  const float* Dv   = (const float*)d_in[5];
  const float* wout = (const float*)d_in[6];
  const float* iaw  = (const float*)d_in[7];
  const float* iab  = (const float*)d_in[8];
  const float* oaw  = (const float*)d_in[9];
  const float* oab  = (const float*)d_in[10];
  const int*   ei   = (const int*)d_in[11];
  (void)in_sizes; (void)n_in; (void)out_size; (void)ws_size;

  float* W = (float*)d_ws;
  size_t o = 0;
  float* xs    = W + o; o += (size_t)NN*128;
  float* rres  = W + o; o += (size_t)NN*128;
  float* delta = W + o; o += (size_t)NN*128;
  float* y2p   = W + o; o += (size_t)NN*128;
  float* Bm    = W + o; o += (size_t)NN*16;
  float* Cm    = W + o; o += (size_t)NN*16;
  float* Amat  = W + o; o += 2048;
  float* dinv1 = W + o; o += NN;
  float* inp   = W + o; o += NN;
  float* outp  = W + o; o += NN;
  _Float16* dxh2 = (_Float16*)(W + o); o += (size_t)NN*64;   // 2 MB (128 h/row)
  _Float16* Bh   = (_Float16*)(W + o); o += (size_t)NN*8;    // 256 KB
  _Float16* stA  = (_Float16*)(W + o); o += (size_t)NN*1024; // fp16 state1, 32 MB
  int* cnt     = (int*)(W + o);
  int* csr_col = cnt + NN;

  uint32_t ki0, ki1, ko0, ko1;
  tf2x32(0u, 42u, 0u, 0u, ki0, ki1);
  tf2x32(0u, 42u, 0u, 1u, ko0, ko1);

  // CSR build: zero counters, then bucket-scatter
  k_zero<<<NN/256, 256, 0, stream>>>(cnt, NN);
  k_scatter<<<NE/256, 256, 0, stream>>>(ei, cnt, csr_col);

  // per-node precompute + layer-0 gates + Amat (8 nodes/block)
  k_nodeprep<<<NN/G, 256, 0, stream>>>(x, ipw, xpw, dtw, iaw, iab, oaw, oab,
                                       alog, ki0, ki1, ko0, ko1,
                                       xs, rres, delta, dxh2, Bm, Bh, Cm,
                                       inp, outp, Amat);

  // spmm0 (rank-1, fp16 gather) + layer-1 update + deg1 + layer-2 self-term
  k_spmm0f<<<NN, 256, 0, stream>>>(cnt, csr_col, inp, outp,
                                   delta, dxh2, Bm, Bh, Cm, Amat,
                                   stA, dinv1, y2p);

  // gated gather + layer-2 + output projection
  k_spmm1fo<<<NN, 256, 0, stream>>>(cnt, csr_col, dinv1, inp, outp,
                                    delta, Cm, Amat, stA, y2p,
                                    xs, rres, Dv, wout, (float*)d_out);
}